// Round 4
// baseline (282.708 us; speedup 1.0000x reference)
//
#include <hip/hip_runtime.h>
#include <stdint.h>

typedef __bf16 bf16x8 __attribute__((ext_vector_type(8)));
typedef float f32x4 __attribute__((ext_vector_type(4)));
typedef unsigned short u16x8 __attribute__((ext_vector_type(8)));

constexpr int NB = 8;     // batches
constexpr int N  = 2048;  // nodes
constexpr int F  = 128;   // features (in == out)

__device__ __forceinline__ unsigned short bf16r(float f) {
    unsigned u = __float_as_uint(f);
    return (unsigned short)((u + 0x7FFFu + ((u >> 16) & 1u)) >> 16);
}
__device__ __forceinline__ float bf2f(unsigned short s) {
    return __uint_as_float(((unsigned)s) << 16);
}

// ---------------------------------------------------------------------------
// Wb element layout (MFMA-B-operand native):
//   E(b, n, o) = b*N*F + (n>>3)*1024 + o*8 + (n&7)
// Lane needing B[k = kb+quad*8 .. +8][o] reads 16 contiguous bytes at
//   byte(b) + ((kb>>3)+quad)*2048 + o*16.
// ---------------------------------------------------------------------------

// K1: Wb[b][n][o] (bf16, blocked layout) = sum_f h[b][n][f] * W[o][f]
__global__ __launch_bounds__(256) void k1_wh(const float* __restrict__ h,
                                             const float* __restrict__ W,
                                             unsigned short* __restrict__ Wb) {
    const int tid  = threadIdx.x;
    const int lane = tid & 63, wid = tid >> 6;
    const int quad = lane >> 4, l15 = lane & 15;
    const int wm = wid >> 1, wn = wid & 1;
    const int m0 = blockIdx.x * 64;
    const int batch = m0 >> 11;
    const int nbase = m0 & 2047;

    f32x4 acc[2][4] = {};

#pragma unroll
    for (int kk = 0; kk < 4; ++kk) {
        const int k = kk * 32 + quad * 8;
        bf16x8 afr[2], bfr[4];
#pragma unroll
        for (int rt = 0; rt < 2; ++rt) {
            const float* src = h + (size_t)(m0 + wm * 32 + rt * 16 + l15) * F + k;
            float4 x0 = *(const float4*)src;
            float4 x1 = *(const float4*)(src + 4);
            afr[rt][0] = (__bf16)x0.x; afr[rt][1] = (__bf16)x0.y;
            afr[rt][2] = (__bf16)x0.z; afr[rt][3] = (__bf16)x0.w;
            afr[rt][4] = (__bf16)x1.x; afr[rt][5] = (__bf16)x1.y;
            afr[rt][6] = (__bf16)x1.z; afr[rt][7] = (__bf16)x1.w;
        }
#pragma unroll
        for (int ct = 0; ct < 4; ++ct) {
            const int o = wn * 64 + ct * 16 + l15;
            const float* src = W + (size_t)o * F + k;
            float4 x0 = *(const float4*)src;
            float4 x1 = *(const float4*)(src + 4);
            bfr[ct][0] = (__bf16)x0.x; bfr[ct][1] = (__bf16)x0.y;
            bfr[ct][2] = (__bf16)x0.z; bfr[ct][3] = (__bf16)x0.w;
            bfr[ct][4] = (__bf16)x1.x; bfr[ct][5] = (__bf16)x1.y;
            bfr[ct][6] = (__bf16)x1.z; bfr[ct][7] = (__bf16)x1.w;
        }
#pragma unroll
        for (int rt = 0; rt < 2; ++rt)
#pragma unroll
            for (int ct = 0; ct < 4; ++ct)
                acc[rt][ct] = __builtin_amdgcn_mfma_f32_16x16x32_bf16(
                    afr[rt], bfr[ct], acc[rt][ct], 0, 0, 0);
    }

#pragma unroll
    for (int rt = 0; rt < 2; ++rt)
#pragma unroll
        for (int ct = 0; ct < 4; ++ct) {
            const int o  = wn * 64 + ct * 16 + l15;
            const int n0 = nbase + wm * 32 + rt * 16 + quad * 4;
            size_t off = (size_t)batch * N * F + (size_t)(n0 >> 3) * 1024 + o * 8 + (n0 & 7);
            ushort4 v;
            v.x = bf16r(acc[rt][ct][0]); v.y = bf16r(acc[rt][ct][1]);
            v.z = bf16r(acc[rt][ct][2]); v.w = bf16r(acc[rt][ct][3]);
            *(ushort4*)&Wb[off] = v;
        }
}

// K2: one wave per 8-node group. e[j] = sum_o Wb[j][o]*a2[o]; p = exp(e);
//     p16 = bf16(p);  Wb2[j][o] = bf16(p * Wb[j][o])
__global__ __launch_bounds__(256) void k2_scale(const unsigned short* __restrict__ Wb,
                                                const float* __restrict__ a,
                                                unsigned short* __restrict__ Wb2,
                                                unsigned short* __restrict__ p16) {
    const int tid  = threadIdx.x;
    const int lane = tid & 63, wid = tid >> 6;
    const int g = blockIdx.x * 4 + wid;      // group id, 0 .. NB*N/8-1
    const int b = g >> 8, grp = g & 255;

    const size_t base = (size_t)b * N * F + (size_t)grp * 1024 + lane * 16;
    bf16x8 v0 = *(const bf16x8*)(Wb + base);       // o = 2*lane
    bf16x8 v1 = *(const bf16x8*)(Wb + base + 8);   // o = 2*lane+1

    const float a0 = a[F + 2 * lane], a1 = a[F + 2 * lane + 1];
    float part[8];
#pragma unroll
    for (int nn = 0; nn < 8; ++nn)
        part[nn] = (float)v0[nn] * a0 + (float)v1[nn] * a1;

#pragma unroll
    for (int m = 1; m < 64; m <<= 1)
#pragma unroll
        for (int nn = 0; nn < 8; ++nn)
            part[nn] += __shfl_xor(part[nn], m);

    u16x8 pv;
    float pf[8];
#pragma unroll
    for (int nn = 0; nn < 8; ++nn) {
        unsigned short pb = bf16r(expf(part[nn]));
        pv[nn] = pb;
        pf[nn] = bf2f(pb);     // rounded p for num/denom consistency
    }
    if (lane == 0)
        *(u16x8*)&p16[b * N + grp * 8] = pv;

    bf16x8 w0, w1;
#pragma unroll
    for (int nn = 0; nn < 8; ++nn) {
        w0[nn] = (__bf16)bf2f(bf16r(pf[nn] * (float)v0[nn]));
        w1[nn] = (__bf16)bf2f(bf16r(pf[nn] * (float)v1[nn]));
    }
    *(bf16x8*)(Wb2 + base)     = w0;
    *(bf16x8*)(Wb2 + base + 8) = w1;
}

// K3: out[b][i][o] = (sum_j adj[b][i][j] * Wb2[j][o]) / (sum_j adj * p[j])
// Hand-pipelined: asm global_load_dwordx4 + hand-placed s_waitcnt vmcnt(15).
// Depth-4 chunk pipeline, 5 loads/chunk, 20 always outstanding.
// Block tile 16(i) x 128(o), 4 waves, wave slice 16 x 32 (o = wid*32..+31).
// A (adj rows) shared by all 4 waves via per-CU L1. Grid 1024 = 4 blocks/CU.
__global__ __launch_bounds__(256, 4) void k3_attn(const float* __restrict__ adj,
                                                  const unsigned short* __restrict__ Wb2,
                                                  const unsigned short* __restrict__ p16,
                                                  float* __restrict__ out) {
    const int tid  = threadIdx.x;
    const int lane = tid & 63, wid = tid >> 6;
    const int quad = lane >> 4, l15 = lane & 15;
    const int b  = blockIdx.x >> 7;
    const int i0 = (blockIdx.x & 127) * 16;

    // A: lane reads adj[i0+l15][c*32 + quad*8 .. +8] = 32 contiguous bytes
    const char* aA = (const char*)adj
        + ((size_t)b * N * N + (size_t)(i0 + l15) * N) * sizeof(float) + quad * 32;
    // B: 16 bytes at  base + quad*2048 + o*16 + c*8192,  o = wid*32 + ct*16 + l15
    const char* bB = (const char*)Wb2 + (size_t)b * N * F * 2
        + quad * 2048 + wid * 512 + l15 * 16;
    // p: 16 bytes at base + quad*16 + c*64 (quad-broadcast)
    const char* pB = (const char*)p16 + (size_t)b * N * 2 + quad * 16;

    f32x4 xa[4][2], xb[4][2], xp[4];
    f32x4 acc[2] = {};
    f32x4 dacc = {};

#define ISSUE(SLOT, CC) do {                                                  \
    uint64_t _a = (uint64_t)(aA + (size_t)(CC) * 128);                        \
    uint64_t _b = (uint64_t)(bB + (size_t)(CC) * 8192);                       \
    uint64_t _p = (uint64_t)(pB + (size_t)(CC) * 64);                         \
    asm volatile("global_load_dwordx4 %0, %2, off nt\n\t"                     \
                 "global_load_dwordx4 %1, %2, off offset:16 nt"               \
        : "=&v"(xa[SLOT][0]), "=&v"(xa[SLOT][1]) : "v"(_a) : "memory");       \
    asm volatile("global_load_dwordx4 %0, %2, off\n\t"                        \
                 "global_load_dwordx4 %1, %2, off offset:256"                 \
        : "=&v"(xb[SLOT][0]), "=&v"(xb[SLOT][1]) : "v"(_b) : "memory");       \
    asm volatile("global_load_dwordx4 %0, %1, off"                            \
        : "=&v"(xp[SLOT]) : "v"(_p) : "memory");                              \
} while (0)

#define STEP(SLOT) do {                                                       \
    asm volatile("s_waitcnt vmcnt(15)"                                        \
        : "+v"(xa[SLOT][0]), "+v"(xa[SLOT][1]),                               \
          "+v"(xb[SLOT][0]), "+v"(xb[SLOT][1]), "+v"(xp[SLOT]) :: "memory");  \
    f32x4 x0 = xa[SLOT][0], x1 = xa[SLOT][1];                                 \
    bf16x8 af;                                                                \
    af[0] = (__bf16)x0[0]; af[1] = (__bf16)x0[1];                             \
    af[2] = (__bf16)x0[2]; af[3] = (__bf16)x0[3];                             \
    af[4] = (__bf16)x1[0]; af[5] = (__bf16)x1[1];                             \
    af[6] = (__bf16)x1[2]; af[7] = (__bf16)x1[3];                             \
    acc[0] = __builtin_amdgcn_mfma_f32_16x16x32_bf16(                         \
        af, __builtin_bit_cast(bf16x8, xb[SLOT][0]), acc[0], 0, 0, 0);        \
    acc[1] = __builtin_amdgcn_mfma_f32_16x16x32_bf16(                         \
        af, __builtin_bit_cast(bf16x8, xb[SLOT][1]), acc[1], 0, 0, 0);        \
    dacc   = __builtin_amdgcn_mfma_f32_16x16x32_bf16(                         \
        af, __builtin_bit_cast(bf16x8, xp[SLOT]), dacc, 0, 0, 0);             \
} while (0)

    ISSUE(0, 0); ISSUE(1, 1); ISSUE(2, 2); ISSUE(3, 3);

    for (int c = 0; c < 64; c += 4) {
        int cc;
        STEP(0); cc = c + 4; if (cc > 63) cc = 63; ISSUE(0, cc);
        STEP(1); cc = c + 5; if (cc > 63) cc = 63; ISSUE(1, cc);
        STEP(2); cc = c + 6; if (cc > 63) cc = 63; ISSUE(2, cc);
        STEP(3); cc = c + 7; if (cc > 63) cc = 63; ISSUE(3, cc);
    }
    asm volatile("s_waitcnt vmcnt(0)" ::: "memory");

#undef ISSUE
#undef STEP

    float inv[4];
#pragma unroll
    for (int g = 0; g < 4; ++g) inv[g] = 1.0f / dacc[g];

    float* ob = out + (size_t)b * N * F;
#pragma unroll
    for (int ct = 0; ct < 2; ++ct) {
        const int o = wid * 32 + ct * 16 + l15;
#pragma unroll
        for (int g = 0; g < 4; ++g) {
            const int i = i0 + quad * 4 + g;
            __builtin_nontemporal_store(acc[ct][g] * inv[g], &ob[(size_t)i * F + o]);
        }
    }
}

// ---------------------------------------------------------------------------
extern "C" void kernel_launch(void* const* d_in, const int* in_sizes, int n_in,
                              void* d_out, int out_size, void* d_ws, size_t ws_size,
                              hipStream_t stream) {
    const float* h   = (const float*)d_in[0];
    const float* adj = (const float*)d_in[1];
    const float* W   = (const float*)d_in[2];
    const float* a   = (const float*)d_in[3];
    float* out = (float*)d_out;

    unsigned short* Wb  = (unsigned short*)d_ws;                          // 4 MB
    unsigned short* Wb2 = (unsigned short*)((char*)d_ws + (4u << 20));    // 4 MB
    unsigned short* p16 = (unsigned short*)((char*)d_ws + (8u << 20));    // 32 KB

    k1_wh<<<NB * N / 64, 256, 0, stream>>>(h, W, Wb);
    k2_scale<<<NB * N / (8 * 4), 256, 0, stream>>>(Wb, a, Wb2, p16);
    k3_attn<<<NB * (N / 16), 256, 0, stream>>>(adj, Wb2, p16, out);
}

// Round 5
// 227.514 us; speedup vs baseline: 1.2426x; 1.2426x over previous
//
#include <hip/hip_runtime.h>
#include <stdint.h>

#define AS1 __attribute__((address_space(1)))
#define AS3 __attribute__((address_space(3)))

typedef __bf16 bf16x8 __attribute__((ext_vector_type(8)));
typedef float f32x4 __attribute__((ext_vector_type(4)));
typedef unsigned short u16x8 __attribute__((ext_vector_type(8)));

constexpr int NB = 8;     // batches
constexpr int N  = 2048;  // nodes
constexpr int F  = 128;   // features (in == out)

__device__ __forceinline__ unsigned short bf16r(float f) {
    unsigned u = __float_as_uint(f);
    return (unsigned short)((u + 0x7FFFu + ((u >> 16) & 1u)) >> 16);
}
__device__ __forceinline__ float bf2f(unsigned short s) {
    return __uint_as_float(((unsigned)s) << 16);
}

// ---------------------------------------------------------------------------
// Wb element layout (MFMA-B-operand native):
//   E(b, n, o) = b*N*F + (n>>3)*1024 + o*8 + (n&7)
// Lane needing B[k = kb+quad*8 .. +8][o] reads 16 contiguous bytes at
//   byte(b) + ((kb>>3)+quad)*2048 + o*16.
// ---------------------------------------------------------------------------

// K1: Wb[b][n][o] (bf16, blocked layout) = sum_f h[b][n][f] * W[o][f]
__global__ __launch_bounds__(256) void k1_wh(const float* __restrict__ h,
                                             const float* __restrict__ W,
                                             unsigned short* __restrict__ Wb) {
    const int tid  = threadIdx.x;
    const int lane = tid & 63, wid = tid >> 6;
    const int quad = lane >> 4, l15 = lane & 15;
    const int wm = wid >> 1, wn = wid & 1;
    const int m0 = blockIdx.x * 64;
    const int batch = m0 >> 11;
    const int nbase = m0 & 2047;

    f32x4 acc[2][4] = {};

#pragma unroll
    for (int kk = 0; kk < 4; ++kk) {
        const int k = kk * 32 + quad * 8;
        bf16x8 afr[2], bfr[4];
#pragma unroll
        for (int rt = 0; rt < 2; ++rt) {
            const float* src = h + (size_t)(m0 + wm * 32 + rt * 16 + l15) * F + k;
            float4 x0 = *(const float4*)src;
            float4 x1 = *(const float4*)(src + 4);
            afr[rt][0] = (__bf16)x0.x; afr[rt][1] = (__bf16)x0.y;
            afr[rt][2] = (__bf16)x0.z; afr[rt][3] = (__bf16)x0.w;
            afr[rt][4] = (__bf16)x1.x; afr[rt][5] = (__bf16)x1.y;
            afr[rt][6] = (__bf16)x1.z; afr[rt][7] = (__bf16)x1.w;
        }
#pragma unroll
        for (int ct = 0; ct < 4; ++ct) {
            const int o = wn * 64 + ct * 16 + l15;
            const float* src = W + (size_t)o * F + k;
            float4 x0 = *(const float4*)src;
            float4 x1 = *(const float4*)(src + 4);
            bfr[ct][0] = (__bf16)x0.x; bfr[ct][1] = (__bf16)x0.y;
            bfr[ct][2] = (__bf16)x0.z; bfr[ct][3] = (__bf16)x0.w;
            bfr[ct][4] = (__bf16)x1.x; bfr[ct][5] = (__bf16)x1.y;
            bfr[ct][6] = (__bf16)x1.z; bfr[ct][7] = (__bf16)x1.w;
        }
#pragma unroll
        for (int rt = 0; rt < 2; ++rt)
#pragma unroll
            for (int ct = 0; ct < 4; ++ct)
                acc[rt][ct] = __builtin_amdgcn_mfma_f32_16x16x32_bf16(
                    afr[rt], bfr[ct], acc[rt][ct], 0, 0, 0);
    }

#pragma unroll
    for (int rt = 0; rt < 2; ++rt)
#pragma unroll
        for (int ct = 0; ct < 4; ++ct) {
            const int o  = wn * 64 + ct * 16 + l15;
            const int n0 = nbase + wm * 32 + rt * 16 + quad * 4;
            size_t off = (size_t)batch * N * F + (size_t)(n0 >> 3) * 1024 + o * 8 + (n0 & 7);
            ushort4 v;
            v.x = bf16r(acc[rt][ct][0]); v.y = bf16r(acc[rt][ct][1]);
            v.z = bf16r(acc[rt][ct][2]); v.w = bf16r(acc[rt][ct][3]);
            *(ushort4*)&Wb[off] = v;
        }
}

// K2: one wave per 8-node group. e[j] = sum_o Wb[j][o]*a2[o]; p = exp(e);
//     p16 = bf16(p);  Wb2[j][o] = bf16(p * Wb[j][o])
__global__ __launch_bounds__(256) void k2_scale(const unsigned short* __restrict__ Wb,
                                                const float* __restrict__ a,
                                                unsigned short* __restrict__ Wb2,
                                                unsigned short* __restrict__ p16) {
    const int tid  = threadIdx.x;
    const int lane = tid & 63, wid = tid >> 6;
    const int g = blockIdx.x * 4 + wid;      // group id, 0 .. NB*N/8-1
    const int b = g >> 8, grp = g & 255;

    const size_t base = (size_t)b * N * F + (size_t)grp * 1024 + lane * 16;
    bf16x8 v0 = *(const bf16x8*)(Wb + base);       // o = 2*lane
    bf16x8 v1 = *(const bf16x8*)(Wb + base + 8);   // o = 2*lane+1

    const float a0 = a[F + 2 * lane], a1 = a[F + 2 * lane + 1];
    float part[8];
#pragma unroll
    for (int nn = 0; nn < 8; ++nn)
        part[nn] = (float)v0[nn] * a0 + (float)v1[nn] * a1;

#pragma unroll
    for (int m = 1; m < 64; m <<= 1)
#pragma unroll
        for (int nn = 0; nn < 8; ++nn)
            part[nn] += __shfl_xor(part[nn], m);

    u16x8 pv;
    float pf[8];
#pragma unroll
    for (int nn = 0; nn < 8; ++nn) {
        unsigned short pb = bf16r(expf(part[nn]));
        pv[nn] = pb;
        pf[nn] = bf2f(pb);     // rounded p for num/denom consistency
    }
    if (lane == 0)
        *(u16x8*)&p16[b * N + grp * 8] = pv;

    bf16x8 w0, w1;
#pragma unroll
    for (int nn = 0; nn < 8; ++nn) {
        w0[nn] = (__bf16)bf2f(bf16r(pf[nn] * (float)v0[nn]));
        w1[nn] = (__bf16)bf2f(bf16r(pf[nn] * (float)v1[nn]));
    }
    *(bf16x8*)(Wb2 + base)     = w0;
    *(bf16x8*)(Wb2 + base + 8) = w1;
}

// K3: out[b][i][o] = (sum_j adj[b][i][j] * Wb2[j][o]) / (sum_j adj * p[j])
// R1-style dbuf global_load_lds staging of adj; BK=128; block 16(i) x 128(o);
// 4 waves, each the o-slice wid*32..+31 (A shared via LDS). Grid 1024 ->
// 4 blocks/CU so barrier stalls of one block overlap staging of others.
// LDS A-tile: 16 rows x 512 B, 32B-chunk XOR swizzle applied on the GLOBAL
// side (LDS dest of global_load_lds is forced contiguous base+lane*16).
__global__ __launch_bounds__(256, 4) void k3_attn(const float* __restrict__ adj,
                                                  const unsigned short* __restrict__ Wb2,
                                                  const unsigned short* __restrict__ p16,
                                                  float* __restrict__ out) {
    __shared__ __align__(16) float At[2][16 * 128];   // 8 KB per buffer

    const int tid  = threadIdx.x;
    const int lane = tid & 63, wid = tid >> 6;
    const int quad = lane >> 4, l15 = lane & 15;
    const int b  = blockIdx.x >> 7;
    const int i0 = (blockIdx.x & 127) * 16;

    const float* adjb = adj + (size_t)b * N * N;
    const char*  bB   = (const char*)Wb2 + (size_t)b * N * F * 2 + wid * 512 + l15 * 16;
    const unsigned short* pb = p16 + b * N + quad * 8;

    // Staging: 8 KB/chunk = 8 instrs, 2 per wave (s=0,1). Instr (wid,s) fills
    // LDS rows wid*4+s*2 .. +1 (1 KB contiguous). Lane ls16=lane&31 is the
    // 16B-slot in its row ri; global 32B-chunk = (ls16>>1) ^ ri (swizzle).
    const int ls16 = lane & 31;
    const int riB  = wid * 4 + (lane >> 5);
    auto stage = [&](int buf, int c) {
#pragma unroll
        for (int s = 0; s < 2; ++s) {
            const int ri = riB + s * 2;
            const int gf = (((ls16 >> 1) ^ ri) << 3) + ((ls16 & 1) << 2);  // floats
            const float* g = adjb + (size_t)(i0 + ri) * N + c * 128 + gf;
            __builtin_amdgcn_global_load_lds((const AS1 void*)g,
                (AS3 void*)((char*)&At[buf][0] + wid * 2048 + s * 1024), 16, 0, 0);
        }
    };

    f32x4 acc[2] = {};
    f32x4 dacc = {};

    stage(0, 0);

    for (int c = 0; c < 16; ++c) {
        const int cur = c & 1;
        __syncthreads();              // drains stage(c) + prev chunk's LDS reads
        if (c + 1 < 16) stage(cur ^ 1, c + 1);

#pragma unroll
        for (int s = 0; s < 4; ++s) {
            // A frag: row l15, global 32B-chunk s*4+quad -> LDS slot ^l15
            const char* ab = (const char*)&At[cur][0]
                           + l15 * 512 + (((s * 4 + quad) ^ l15) << 5);
            f32x4 x0 = *(const f32x4*)ab;
            f32x4 x1 = *(const f32x4*)(ab + 16);
            // B frags + p frag (L2/L1-resident plain loads)
            const char* bp = bB + ((size_t)c * 16 + s * 4 + quad) * 2048;
            bf16x8 b0 = *(const bf16x8*)bp;
            bf16x8 b1 = *(const bf16x8*)(bp + 256);
            bf16x8 pv = *(const bf16x8*)(pb + c * 128 + s * 32);

            bf16x8 af;   // adj in {0,1}: cvt exact; p folded into B
            af[0] = (__bf16)x0[0]; af[1] = (__bf16)x0[1];
            af[2] = (__bf16)x0[2]; af[3] = (__bf16)x0[3];
            af[4] = (__bf16)x1[0]; af[5] = (__bf16)x1[1];
            af[6] = (__bf16)x1[2]; af[7] = (__bf16)x1[3];

            acc[0] = __builtin_amdgcn_mfma_f32_16x16x32_bf16(af, b0, acc[0], 0, 0, 0);
            acc[1] = __builtin_amdgcn_mfma_f32_16x16x32_bf16(af, b1, acc[1], 0, 0, 0);
            dacc   = __builtin_amdgcn_mfma_f32_16x16x32_bf16(af, pv, dacc, 0, 0, 0);
        }
    }

    // dacc reg g = denom for row quad*4+g — same row mapping as acc.
    float inv[4];
#pragma unroll
    for (int g = 0; g < 4; ++g) inv[g] = 1.0f / dacc[g];

    float* ob = out + (size_t)b * N * F;
#pragma unroll
    for (int ct = 0; ct < 2; ++ct) {
        const int o = wid * 32 + ct * 16 + l15;
#pragma unroll
        for (int g = 0; g < 4; ++g) {
            const int i = i0 + quad * 4 + g;
            ob[(size_t)i * F + o] = acc[ct][g] * inv[g];
        }
    }
}

// ---------------------------------------------------------------------------
extern "C" void kernel_launch(void* const* d_in, const int* in_sizes, int n_in,
                              void* d_out, int out_size, void* d_ws, size_t ws_size,
                              hipStream_t stream) {
    const float* h   = (const float*)d_in[0];
    const float* adj = (const float*)d_in[1];
    const float* W   = (const float*)d_in[2];
    const float* a   = (const float*)d_in[3];
    float* out = (float*)d_out;

    unsigned short* Wb  = (unsigned short*)d_ws;                          // 4 MB
    unsigned short* Wb2 = (unsigned short*)((char*)d_ws + (4u << 20));    // 4 MB
    unsigned short* p16 = (unsigned short*)((char*)d_ws + (8u << 20));    // 32 KB

    k1_wh<<<NB * N / 64, 256, 0, stream>>>(h, W, Wb);
    k2_scale<<<NB * N / (8 * 4), 256, 0, stream>>>(Wb, a, Wb2, p16);
    k3_attn<<<NB * (N / 16), 256, 0, stream>>>(adj, Wb2, p16, out);
}